// Round 6
// baseline (840.492 us; speedup 1.0000x reference)
//
#include <hip/hip_runtime.h>
#include <stdint.h>

typedef unsigned short u16;
typedef __bf16 bf16x8 __attribute__((ext_vector_type(8)));
typedef float f32x4 __attribute__((ext_vector_type(4)));

#define MFMA(a, b, c) __builtin_amdgcn_mfma_f32_16x16x32_bf16(a, b, c, 0, 0, 0)

__device__ __forceinline__ u16 f2bf(float f) {
    union { float f; unsigned u; } v; v.f = f;
    unsigned r = v.u + 0x7fffu + ((v.u >> 16) & 1u);
    return (u16)(r >> 16);
}
__device__ __forceinline__ float bf2f(u16 h) {
    union { unsigned u; float f; } v; v.u = ((unsigned)h) << 16; return v.f;
}
__device__ __forceinline__ bf16x8 as_frag(uint4 u) {
    union { uint4 u; bf16x8 b; } v; v.u = u; return v.b;
}
__device__ __forceinline__ bf16x8 ldg_frag(const u16* p) {
    return as_frag(*reinterpret_cast<const uint4*>(p));
}
// weight-row permutation so swapped-GEMM output packs into natural frag order
__device__ __forceinline__ int rowmap(int t, int i) {
    return 32 * (t >> 1) + 8 * (i >> 2) + 4 * (t & 1) + (i & 3);
}

// ---- normal orientation: C[row][col=chan], one A-group (node kernels) ----
template <int KT>
__device__ __forceinline__ void gemm_acc(const bf16x8* a, const u16* __restrict__ W, int ldw,
                                         f32x4* acc, int c16, int q4) {
#pragma unroll
    for (int n = 0; n < 8; n++) {
        const u16* wp = W + (size_t)(n * 16 + c16) * ldw + q4 * 8;
#pragma unroll
        for (int k = 0; k < KT; k++) {
            bf16x8 b = ldg_frag(wp + k * 32);
            acc[n] = MFMA(a[k], b, acc[n]);
        }
    }
}

// GroupNorm on swapped layout: lane holds 32 chans of one edge
__device__ __forceinline__ void gn_t(f32x4* acc, const float* __restrict__ gb, bool relu, int q4) {
    float s = 0.f, s2 = 0.f;
#pragma unroll
    for (int t = 0; t < 8; t++)
#pragma unroll
        for (int r = 0; r < 4; r++) { float x = acc[t][r]; s += x; s2 = fmaf(x, x, s2); }
    s += __shfl_xor(s, 16, 64); s += __shfl_xor(s, 32, 64);
    s2 += __shfl_xor(s2, 16, 64); s2 += __shfl_xor(s2, 32, 64);
    float mean = s * (1.f / 128.f);
    float var = fmaf(s2, 1.f / 128.f, -mean * mean);
    float rstd = rsqrtf(var + 1e-5f);
#pragma unroll
    for (int t = 0; t < 8; t++) {
        const float4* g4 = reinterpret_cast<const float4*>(gb + (t * 16 + q4 * 4) * 2);
        float4 p01 = g4[0], p23 = g4[1];
        float gv[4] = {p01.x, p01.z, p23.x, p23.z};
        float bv[4] = {p01.y, p01.w, p23.y, p23.w};
#pragma unroll
        for (int r = 0; r < 4; r++) {
            float y = fmaf((acc[t][r] - mean) * rstd, gv[r], bv[r]);
            acc[t][r] = relu ? fmaxf(y, 0.f) : y;
        }
    }
}

__device__ __forceinline__ bf16x8 pack_frag(f32x4 lo, f32x4 hi) {
    union { u16 s[8]; bf16x8 b; } t;
#pragma unroll
    for (int j = 0; j < 4; j++) { t.s[j] = f2bf(lo[j]); t.s[4 + j] = f2bf(hi[j]); }
    return t.b;
}

// GroupNorm on C-layout acc[n][r] (node kernels)
__device__ __forceinline__ void gn_c(f32x4* acc, const float* __restrict__ g,
                                     const float* __restrict__ b, bool relu, int c16) {
    float gs[8], bs[8];
#pragma unroll
    for (int n = 0; n < 8; n++) { gs[n] = g[n * 16 + c16]; bs[n] = b[n * 16 + c16]; }
#pragma unroll
    for (int r = 0; r < 4; r++) {
        float s = 0.f, s2 = 0.f;
#pragma unroll
        for (int n = 0; n < 8; n++) { float x = acc[n][r]; s += x; s2 = fmaf(x, x, s2); }
#pragma unroll
        for (int m = 1; m < 16; m <<= 1) { s += __shfl_xor(s, m, 64); s2 += __shfl_xor(s2, m, 64); }
        float mean = s * (1.f / 128.f);
        float var = fmaf(s2, 1.f / 128.f, -mean * mean);
        float rstd = rsqrtf(var + 1e-5f);
#pragma unroll
        for (int n = 0; n < 8; n++) {
            float y = fmaf((acc[n][r] - mean) * rstd, gs[n], bs[n]);
            acc[n][r] = relu ? fmaxf(y, 0.f) : y;
        }
    }
}

// ---------------- prep ----------------
__global__ __launch_bounds__(256) void k_prep(
    const float* __restrict__ dW2s, const float* __restrict__ qWs, const float* __restrict__ cW1s,
    const float* __restrict__ cW2s, const float* __restrict__ aWs, const float* __restrict__ lWs,
    const float* __restrict__ actors, const float* __restrict__ metaW,
    const float* __restrict__ dW1s, const float* __restrict__ db1s,
    const float* __restrict__ dg2s, const float* __restrict__ dbt2s,
    const float* __restrict__ qgs, const float* __restrict__ qbs,
    const float* __restrict__ cg1s, const float* __restrict__ cb1s,
    u16* __restrict__ o_dW2p, u16* __restrict__ o_qW, u16* __restrict__ o_cW1p,
    u16* __restrict__ o_cW2, u16* __restrict__ o_aW, u16* __restrict__ o_lW,
    u16* __restrict__ o_actb, u16* __restrict__ o_mWf, float* __restrict__ o_mWe,
    float* __restrict__ o_dw1p, float* __restrict__ o_gb) {
    int idx = blockIdx.x * 256 + threadIdx.x;
    if (idx >= 412672) return;
    if (idx < 32768) {
        int i = idx >> 14, rem = idx & 16383, ro = rem >> 7, col = rem & 127;
        o_dW2p[idx] = f2bf(dW2s[i * 16384 + rowmap(ro >> 4, ro & 15) * 128 + col]);
    } else if (idx < 65536) {
        int j = idx - 32768; o_qW[j] = f2bf(qWs[j]);   // natural (used by nodeA)
    } else if (idx < 163840) {
        int j = idx - 65536, i = j / 49152, rem = j - i * 49152, ro = rem / 384, col = rem - ro * 384;
        o_cW1p[j] = f2bf(cW1s[i * 49152 + rowmap(ro >> 4, ro & 15) * 384 + col]);
    } else if (idx < 196608) { int j = idx - 163840; o_cW2[j] = f2bf(cW2s[j]); }
    else if (idx < 229376) { int j = idx - 196608; o_aW[j] = f2bf(aWs[j]); }
    else if (idx < 262144) { int j = idx - 229376; o_lW[j] = f2bf(lWs[j]); }
    else if (idx < 393216) { int j = idx - 262144; o_actb[j] = f2bf(actors[j]); }
    else if (idx < 409600) { int j = idx - 393216; o_mWf[j] = f2bf(metaW[(j >> 7) * 132 + (j & 127)]); }
    else if (idx < 410112) { int j = idx - 409600; o_mWe[j] = metaW[(j >> 2) * 132 + 128 + (j & 3)]; }
    else if (idx < 411136) {
        int j = idx - 410112, i = j >> 9, col = (j >> 2) & 127, t = j & 3;
        float v = (t == 0) ? dW1s[i * 256 + col * 2]
                : (t == 1) ? dW1s[i * 256 + col * 2 + 1]
                : (t == 2) ? db1s[i * 128 + col] : 0.f;
        o_dw1p[j] = v;
    } else {
        int j = idx - 411136;           // 3 tables x 2 layers x 128 x {g,b}
        int tb = j >> 9, rem = j & 511, i = rem >> 8, q = rem & 255, o = q >> 1, f = q & 1;
        const float* gsrc = (tb == 0) ? dg2s : (tb == 1) ? qgs : cg1s;
        const float* bsrc = (tb == 0) ? dbt2s : (tb == 1) ? qbs : cb1s;
        int src = i * 128 + rowmap(o >> 4, o & 15);
        o_gb[j] = f ? bsrc[src] : gsrc[src];
    }
}

// ---------------- meta ----------------
__global__ __launch_bounds__(256) void k_meta(
    const float* __restrict__ feat, const float* __restrict__ turn,
    const float* __restrict__ ctrl, const float* __restrict__ inter,
    const u16* __restrict__ mWf, const float* __restrict__ mWe,
    const float* __restrict__ g, const float* __restrict__ b, u16* __restrict__ out) {
    int lane = threadIdx.x & 63, wv = threadIdx.x >> 6;
    int c16 = lane & 15, q4 = lane >> 4;
    int m0 = (blockIdx.x * 4 + wv) * 16;
    bf16x8 a[4];
    const float* xr = feat + (size_t)(m0 + c16) * 128 + q4 * 8;
#pragma unroll
    for (int k = 0; k < 4; k++) {
        float4 u0 = *reinterpret_cast<const float4*>(xr + k * 32);
        float4 u1 = *reinterpret_cast<const float4*>(xr + k * 32 + 4);
        union { u16 s[8]; bf16x8 b; } t;
        t.s[0] = f2bf(u0.x); t.s[1] = f2bf(u0.y); t.s[2] = f2bf(u0.z); t.s[3] = f2bf(u0.w);
        t.s[4] = f2bf(u1.x); t.s[5] = f2bf(u1.y); t.s[6] = f2bf(u1.z); t.s[7] = f2bf(u1.w);
        a[k] = t.b;
    }
    f32x4 acc[8] = {};
    gemm_acc<4>(a, mWf, 128, acc, c16, q4);
#pragma unroll
    for (int r = 0; r < 4; r++) {
        int row = m0 + q4 * 4 + r;
        float t0 = turn[2 * row], t1 = turn[2 * row + 1];
        float cv = ctrl[row], iv = inter[row];
#pragma unroll
        for (int n = 0; n < 8; n++) {
            int col = n * 16 + c16;
            float4 we = reinterpret_cast<const float4*>(mWe)[col];
            acc[n][r] += t0 * we.x + t1 * we.y + cv * we.z + iv * we.w;
        }
    }
    gn_c(acc, g, b, true, c16);
#pragma unroll
    for (int r = 0; r < 4; r++) {
        size_t row = m0 + q4 * 4 + r;
#pragma unroll
        for (int n = 0; n < 8; n++) out[row * 128 + n * 16 + c16] = f2bf(acc[n][r]);
    }
}

// ---------------- nodeA: q_node = relu(GN(feat@qW^T)); a = feat@aW^T ----------------
__global__ __launch_bounds__(256) void k_nodeA(
    const u16* __restrict__ featb, const u16* __restrict__ qW, const u16* __restrict__ aW,
    const float* __restrict__ qg, const float* __restrict__ qb,
    u16* __restrict__ q_out, float* __restrict__ a_out) {
    int lane = threadIdx.x & 63, wv = threadIdx.x >> 6;
    int c16 = lane & 15, q4 = lane >> 4;
    int m0 = (blockIdx.x * 4 + wv) * 16;
    bf16x8 a[4];
    const u16* xr = featb + (size_t)(m0 + c16) * 128 + q4 * 8;
#pragma unroll
    for (int k = 0; k < 4; k++) a[k] = ldg_frag(xr + k * 32);
    f32x4 accq[8] = {}, acca[8] = {};
    gemm_acc<4>(a, qW, 128, accq, c16, q4);
    gemm_acc<4>(a, aW, 128, acca, c16, q4);
#pragma unroll
    for (int r = 0; r < 4; r++) {
        size_t row = m0 + q4 * 4 + r;
#pragma unroll
        for (int n = 0; n < 8; n++) a_out[row * 128 + n * 16 + c16] = acca[n][r];
    }
    gn_c(accq, qg, qb, true, c16);
#pragma unroll
    for (int r = 0; r < 4; r++) {
        size_t row = m0 + q4 * 4 + r;
#pragma unroll
        for (int n = 0; n < 8; n++) q_out[row * 128 + n * 16 + c16] = f2bf(accq[n][r]);
    }
}

// ---------------- edge: register-resident, 32 edges/wave, ONE reused acc set ----------------
__global__ __launch_bounds__(256, 3) void k_edge(
    const int* __restrict__ hi, const int* __restrict__ wi,
    const float* __restrict__ mctr, const float* __restrict__ actr,
    const float* __restrict__ dw1p, const u16* __restrict__ dW2p,
    const float* __restrict__ gb_d2,
    const u16* __restrict__ q_node, const u16* __restrict__ actb,
    const u16* __restrict__ cW1p, const float* __restrict__ gb_c1,
    const u16* __restrict__ cW2, float* __restrict__ a_out) {
    int lane = threadIdx.x & 63, wv = threadIdx.x >> 6;
    int c16 = lane & 15, q4 = lane >> 4;
    int bid = (int)blockIdx.x;
    bid = (bid & 7) * 256 + (bid >> 3);  // XCD swizzle (2048 = 8*256, bijective)
    int ebase = bid * 128 + wv * 32;
    int h0 = hi[ebase + c16], w0 = wi[ebase + c16];
    int h1 = hi[ebase + 16 + c16], w1 = wi[ebase + 16 + c16];
    // d1 = relu(d0 @ dW1^T + db1), built directly in B-frag layout (both groups)
    float dx0 = mctr[2 * h0] - actr[2 * w0], dy0 = mctr[2 * h0 + 1] - actr[2 * w0 + 1];
    float dx1 = mctr[2 * h1] - actr[2 * w1], dy1 = mctr[2 * h1 + 1] - actr[2 * w1 + 1];
    bf16x8 bd0[4], bd1[4];
    const float4* w4p = reinterpret_cast<const float4*>(dw1p);
#pragma unroll
    for (int k = 0; k < 4; k++) {
        union { u16 s[8]; uint4 u; } t0, t1;
#pragma unroll
        for (int j = 0; j < 8; j++) {
            float4 w4 = w4p[k * 32 + q4 * 8 + j];
            t0.s[j] = f2bf(fmaxf(fmaf(dx0, w4.x, fmaf(dy0, w4.y, w4.z)), 0.f));
            t1.s[j] = f2bf(fmaxf(fmaf(dx1, w4.x, fmaf(dy1, w4.y, w4.z)), 0.f));
        }
        bd0[k] = as_frag(t0.u); bd1[k] = as_frag(t1.u);
    }
    // ONE accumulator pair reused by all three GEMMs (keeps live acc set at 64 regs)
    f32x4 accA[8] = {}, accB[8] = {};
    // d2 = relu(GN(d1 @ dW2^T)) — swapped, k-outer
#pragma unroll
    for (int k = 0; k < 4; k++) {
#pragma unroll
        for (int t = 0; t < 8; t++) {
            bf16x8 a = ldg_frag(dW2p + (size_t)(t * 16 + c16) * 128 + k * 32 + q4 * 8);
            accA[t] = MFMA(a, bd0[k], accA[t]);
            accB[t] = MFMA(a, bd1[k], accB[t]);
        }
    }
    gn_t(accA, gb_d2, true, q4);
    gn_t(accB, gb_d2, true, q4);
    // pack d2 into frags (reuse bd0/bd1 storage pattern: new frags, acc freed below)
    bf16x8 d2f0[4], d2f1[4];
#pragma unroll
    for (int k = 0; k < 4; k++) {
        d2f0[k] = pack_frag(accA[2 * k], accA[2 * k + 1]);
        d2f1[k] = pack_frag(accB[2 * k], accB[2 * k + 1]);
    }
    // c1 = relu(GN(concat @ cW1^T)) — swapped, k-outer, SAME acc arrays re-zeroed
#pragma unroll
    for (int t = 0; t < 8; t++) { accA[t] = f32x4{0, 0, 0, 0}; accB[t] = f32x4{0, 0, 0, 0}; }
    const u16* qr0 = q_node + (size_t)h0 * 128 + q4 * 8;
    const u16* qr1 = q_node + (size_t)h1 * 128 + q4 * 8;
    const u16* ar0 = actb + (size_t)w0 * 128 + q4 * 8;
    const u16* ar1 = actb + (size_t)w1 * 128 + q4 * 8;
#pragma unroll
    for (int k = 0; k < 12; k++) {
        bf16x8 b0 = (k < 4) ? d2f0[k] : (k < 8) ? ldg_frag(qr0 + (k - 4) * 32)
                                                : ldg_frag(ar0 + (k - 8) * 32);
        bf16x8 b1 = (k < 4) ? d2f1[k] : (k < 8) ? ldg_frag(qr1 + (k - 4) * 32)
                                                : ldg_frag(ar1 + (k - 8) * 32);
#pragma unroll
        for (int t = 0; t < 8; t++) {
            bf16x8 a = ldg_frag(cW1p + (size_t)(t * 16 + c16) * 384 + k * 32 + q4 * 8);
            accA[t] = MFMA(a, b0, accA[t]);
            accB[t] = MFMA(a, b1, accB[t]);
        }
    }
    gn_t(accA, gb_c1, true, q4);
    gn_t(accB, gb_c1, true, q4);
    // pack c1, then c2 = c1 @ cW2^T in NORMAL orientation, SAME acc arrays re-zeroed
    bf16x8 ba0[4], ba1[4];
#pragma unroll
    for (int k = 0; k < 4; k++) {
        ba0[k] = pack_frag(accA[2 * k], accA[2 * k + 1]);
        ba1[k] = pack_frag(accB[2 * k], accB[2 * k + 1]);
    }
#pragma unroll
    for (int t = 0; t < 8; t++) { accA[t] = f32x4{0, 0, 0, 0}; accB[t] = f32x4{0, 0, 0, 0}; }
#pragma unroll
    for (int k = 0; k < 4; k++) {
#pragma unroll
        for (int n = 0; n < 8; n++) {
            bf16x8 b = ldg_frag(cW2 + (size_t)(n * 16 + c16) * 128 + k * 32 + q4 * 8);
            accA[n] = MFMA(ba0[k], b, accA[n]);
            accB[n] = MFMA(ba1[k], b, accB[n]);
        }
    }
    // scatter: C[edge=q4*4+r][chan=n*16+c16] — 16 lanes contiguous per row
#pragma unroll
    for (int r = 0; r < 4; r++) {
        int hr0 = hi[ebase + q4 * 4 + r];
        int hr1 = hi[ebase + 16 + q4 * 4 + r];
        float* dst0 = a_out + (size_t)hr0 * 128 + c16;
        float* dst1 = a_out + (size_t)hr1 * 128 + c16;
#pragma unroll
        for (int n = 0; n < 8; n++) {
            unsafeAtomicAdd(dst0 + n * 16, accA[n][r]);
            unsafeAtomicAdd(dst1 + n * 16, accB[n][r]);
        }
    }
}

// ---------------- nodeB ----------------
__global__ __launch_bounds__(256) void k_nodeB(
    const float* __restrict__ a_in, const float* __restrict__ gg, const float* __restrict__ gb,
    const u16* __restrict__ lW, const float* __restrict__ lg, const float* __restrict__ lb,
    const u16* __restrict__ res, u16* __restrict__ out_bf, float* __restrict__ out_f32) {
    int lane = threadIdx.x & 63, wv = threadIdx.x >> 6;
    int c16 = lane & 15, q4 = lane >> 4;
    int m0 = (blockIdx.x * 4 + wv) * 16;
    const float* xr = a_in + (size_t)(m0 + c16) * 128 + q4 * 8;
    float x[32];
#pragma unroll
    for (int k = 0; k < 4; k++) {
        float4 u0 = *reinterpret_cast<const float4*>(xr + k * 32);
        float4 u1 = *reinterpret_cast<const float4*>(xr + k * 32 + 4);
        x[k * 8 + 0] = u0.x; x[k * 8 + 1] = u0.y; x[k * 8 + 2] = u0.z; x[k * 8 + 3] = u0.w;
        x[k * 8 + 4] = u1.x; x[k * 8 + 5] = u1.y; x[k * 8 + 6] = u1.z; x[k * 8 + 7] = u1.w;
    }
    float s = 0.f, s2 = 0.f;
#pragma unroll
    for (int t = 0; t < 32; t++) { s += x[t]; s2 = fmaf(x[t], x[t], s2); }
    s += __shfl_xor(s, 16, 64); s += __shfl_xor(s, 32, 64);
    s2 += __shfl_xor(s2, 16, 64); s2 += __shfl_xor(s2, 32, 64);
    float mean = s * (1.f / 128.f);
    float var = fmaf(s2, 1.f / 128.f, -mean * mean);
    float rstd = rsqrtf(var + 1e-5f);
    bf16x8 a[4];
#pragma unroll
    for (int k = 0; k < 4; k++) {
        float4 g0 = *reinterpret_cast<const float4*>(gg + k * 32 + q4 * 8);
        float4 g1 = *reinterpret_cast<const float4*>(gg + k * 32 + q4 * 8 + 4);
        float4 b0 = *reinterpret_cast<const float4*>(gb + k * 32 + q4 * 8);
        float4 b1 = *reinterpret_cast<const float4*>(gb + k * 32 + q4 * 8 + 4);
        float gv[8] = {g0.x, g0.y, g0.z, g0.w, g1.x, g1.y, g1.z, g1.w};
        float bv[8] = {b0.x, b0.y, b0.z, b0.w, b1.x, b1.y, b1.z, b1.w};
        union { u16 s[8]; bf16x8 b; } t;
#pragma unroll
        for (int j = 0; j < 8; j++) {
            float y = fmaf((x[k * 8 + j] - mean) * rstd, gv[j], bv[j]);
            t.s[j] = f2bf(fmaxf(y, 0.f));
        }
        a[k] = t.b;
    }
    f32x4 acc[8] = {};
    gemm_acc<4>(a, lW, 128, acc, c16, q4);
    gn_c(acc, lg, lb, false, c16);
#pragma unroll
    for (int r = 0; r < 4; r++) {
        size_t row = m0 + q4 * 4 + r;
#pragma unroll
        for (int n = 0; n < 8; n++) {
            int col = n * 16 + c16;
            float y = acc[n][r] + bf2f(res[row * 128 + col]);
            y = fmaxf(y, 0.f);
            if (out_bf) out_bf[row * 128 + col] = f2bf(y);
            else out_f32[row * 128 + col] = y;
        }
    }
}

extern "C" void kernel_launch(void* const* d_in, const int* in_sizes, int n_in,
                              void* d_out, int out_size, void* d_ws, size_t ws_size,
                              hipStream_t stream) {
    const float* feat = (const float*)d_in[0];
    const float* turn = (const float*)d_in[1];
    const float* ctrl = (const float*)d_in[2];
    const float* inter = (const float*)d_in[3];
    const float* mctr = (const float*)d_in[4];
    const float* actors = (const float*)d_in[5];
    const float* actr = (const float*)d_in[6];
    const int* hi = (const int*)d_in[7];
    const int* wi = (const int*)d_in[8];
    const float* metaW = (const float*)d_in[9];
    const float* metag = (const float*)d_in[10];
    const float* metab = (const float*)d_in[11];
    const float* dW1 = (const float*)d_in[12];
    const float* db1 = (const float*)d_in[13];
    const float* dW2 = (const float*)d_in[14];
    const float* dg2 = (const float*)d_in[15];
    const float* dbt2 = (const float*)d_in[16];
    const float* qW = (const float*)d_in[17];
    const float* qg = (const float*)d_in[18];
    const float* qb = (const float*)d_in[19];
    const float* cW1 = (const float*)d_in[20];
    const float* cg1 = (const float*)d_in[21];
    const float* cb1 = (const float*)d_in[22];
    const float* cW2 = (const float*)d_in[23];
    const float* aW = (const float*)d_in[24];
    const float* ngg = (const float*)d_in[25];
    const float* ngb = (const float*)d_in[26];
    const float* lW = (const float*)d_in[27];
    const float* lg = (const float*)d_in[28];
    const float* lb = (const float*)d_in[29];

    char* ws = (char*)d_ws;
    u16* feat0 = (u16*)(ws);                    // 33554432 B
    u16* feat1 = (u16*)(ws + 33554432);         // 33554432 B
    u16* qbuf = (u16*)(ws + 67108864);          // 33554432 B
    u16* actb = (u16*)(ws + 100663296);         // 262144 B
    u16* wmWf = (u16*)(ws + 100925440);         // 32768 B
    u16* wdW2p = (u16*)(ws + 100958208);        // 65536 B
    u16* wqW = (u16*)(ws + 101023744);          // 65536 B
    u16* wcW1p = (u16*)(ws + 101089280);        // 196608 B
    u16* wcW2 = (u16*)(ws + 101285888);         // 65536 B
    u16* waW = (u16*)(ws + 101351424);          // 65536 B
    u16* wlW = (u16*)(ws + 101416960);          // 65536 B
    float* wmWe = (float*)(ws + 101482496);     // 2048 B
    float* wdw1p = (float*)(ws + 101484544);    // 4096 B
    float* gball = (float*)(ws + 101488640);    // 6144 B
    float* abuf = (float*)d_out;                // d_out doubles as f32 scatter buffer

    k_prep<<<1613, 256, 0, stream>>>(dW2, qW, cW1, cW2, aW, lW, actors, metaW, dW1, db1,
                                     dg2, dbt2, qg, qb, cg1, cb1,
                                     wdW2p, wqW, wcW1p, wcW2, waW, wlW, actb, wmWf, wmWe,
                                     wdw1p, gball);
    k_meta<<<2048, 256, 0, stream>>>(feat, turn, ctrl, inter, wmWf, wmWe, metag, metab, feat0);
    for (int i = 0; i < 2; i++) {
        const u16* fcur = i ? feat1 : feat0;
        k_nodeA<<<2048, 256, 0, stream>>>(fcur, wqW + i * 16384, waW + i * 16384,
                                          qg + i * 128, qb + i * 128, qbuf, abuf);
        k_edge<<<2048, 256, 0, stream>>>(hi, wi, mctr, actr, wdw1p + i * 512, wdW2p + i * 16384,
                                         gball + i * 256, qbuf, actb,
                                         wcW1p + i * 49152, gball + 1024 + i * 256,
                                         wcW2 + i * 16384, abuf);
        k_nodeB<<<2048, 256, 0, stream>>>(abuf, ngg + i * 128, ngb + i * 128, wlW + i * 16384,
                                          lg + i * 128, lb + i * 128, fcur,
                                          i ? nullptr : feat1, i ? (float*)d_out : nullptr);
    }
}

// Round 10
// 672.052 us; speedup vs baseline: 1.2506x; 1.2506x over previous
//
#include <hip/hip_runtime.h>
#include <stdint.h>

typedef unsigned short u16;
typedef __bf16 bf16x8 __attribute__((ext_vector_type(8)));
typedef float f32x4 __attribute__((ext_vector_type(4)));

#define MFMA(a, b, c) __builtin_amdgcn_mfma_f32_16x16x32_bf16(a, b, c, 0, 0, 0)

__device__ __forceinline__ u16 f2bf(float f) {
    union { float f; unsigned u; } v; v.f = f;
    unsigned r = v.u + 0x7fffu + ((v.u >> 16) & 1u);
    return (u16)(r >> 16);
}
__device__ __forceinline__ float bf2f(u16 h) {
    union { unsigned u; float f; } v; v.u = ((unsigned)h) << 16; return v.f;
}
__device__ __forceinline__ bf16x8 as_frag(uint4 u) {
    union { uint4 u; bf16x8 b; } v; v.u = u; return v.b;
}
__device__ __forceinline__ bf16x8 ldg_frag(const u16* p) {
    return as_frag(*reinterpret_cast<const uint4*>(p));
}
// weight-row permutation so swapped-GEMM output packs into natural frag order
__device__ __forceinline__ int rowmap(int t, int i) {
    return 32 * (t >> 1) + 8 * (i >> 2) + 4 * (t & 1) + (i & 3);
}

// ---- stage a 128x128 bf16 tile into LDS, XOR-swizzled 16B granules ----
template <int SRC_LDU>  // source row stride in u16
__device__ __forceinline__ void stage128(const u16* __restrict__ src, u16* dst, int tid, int nt) {
    for (int c = tid; c < 2048; c += nt) {
        int row = c >> 4, j = c & 15;
        int js = (j & 8) | ((j ^ row) & 7);
        *reinterpret_cast<uint4*>(dst + row * 128 + js * 8) =
            *reinterpret_cast<const uint4*>(src + row * SRC_LDU + j * 8);
    }
}
__device__ __forceinline__ bf16x8 lds_w(const u16* base, int row, int byteoff) {
    int off = row * 256 + (byteoff ^ ((row & 7) << 4));
    return as_frag(*reinterpret_cast<const uint4*>(reinterpret_cast<const char*>(base) + off));
}

// ---- normal orientation: C[row][col=chan], one A-group (node kernels, round-6 form) ----
template <int KT>
__device__ __forceinline__ void gemm_acc(const bf16x8* a, const u16* __restrict__ W, int ldw,
                                         f32x4* acc, int c16, int q4) {
#pragma unroll
    for (int n = 0; n < 8; n++) {
        const u16* wp = W + (size_t)(n * 16 + c16) * ldw + q4 * 8;
#pragma unroll
        for (int k = 0; k < KT; k++) {
            bf16x8 b = ldg_frag(wp + k * 32);
            acc[n] = MFMA(a[k], b, acc[n]);
        }
    }
}

// GroupNorm on swapped layout: lane holds 32 chans of one edge
__device__ __forceinline__ void gn_t(f32x4* acc, const float* __restrict__ gb, bool relu, int q4) {
    float s = 0.f, s2 = 0.f;
#pragma unroll
    for (int t = 0; t < 8; t++)
#pragma unroll
        for (int r = 0; r < 4; r++) { float x = acc[t][r]; s += x; s2 = fmaf(x, x, s2); }
    s += __shfl_xor(s, 16, 64); s += __shfl_xor(s, 32, 64);
    s2 += __shfl_xor(s2, 16, 64); s2 += __shfl_xor(s2, 32, 64);
    float mean = s * (1.f / 128.f);
    float var = fmaf(s2, 1.f / 128.f, -mean * mean);
    float rstd = rsqrtf(var + 1e-5f);
#pragma unroll
    for (int t = 0; t < 8; t++) {
        const float4* g4 = reinterpret_cast<const float4*>(gb + (t * 16 + q4 * 4) * 2);
        float4 p01 = g4[0], p23 = g4[1];
        float gv[4] = {p01.x, p01.z, p23.x, p23.z};
        float bv[4] = {p01.y, p01.w, p23.y, p23.w};
#pragma unroll
        for (int r = 0; r < 4; r++) {
            float y = fmaf((acc[t][r] - mean) * rstd, gv[r], bv[r]);
            acc[t][r] = relu ? fmaxf(y, 0.f) : y;
        }
    }
}

__device__ __forceinline__ bf16x8 pack_frag(f32x4 lo, f32x4 hi) {
    union { u16 s[8]; bf16x8 b; } t;
#pragma unroll
    for (int j = 0; j < 4; j++) { t.s[j] = f2bf(lo[j]); t.s[4 + j] = f2bf(hi[j]); }
    return t.b;
}

// GroupNorm on C-layout acc[n][r] (node kernels)
__device__ __forceinline__ void gn_c(f32x4* acc, const float* __restrict__ g,
                                     const float* __restrict__ b, bool relu, int c16) {
    float gs[8], bs[8];
#pragma unroll
    for (int n = 0; n < 8; n++) { gs[n] = g[n * 16 + c16]; bs[n] = b[n * 16 + c16]; }
#pragma unroll
    for (int r = 0; r < 4; r++) {
        float s = 0.f, s2 = 0.f;
#pragma unroll
        for (int n = 0; n < 8; n++) { float x = acc[n][r]; s += x; s2 = fmaf(x, x, s2); }
#pragma unroll
        for (int m = 1; m < 16; m <<= 1) { s += __shfl_xor(s, m, 64); s2 += __shfl_xor(s2, m, 64); }
        float mean = s * (1.f / 128.f);
        float var = fmaf(s2, 1.f / 128.f, -mean * mean);
        float rstd = rsqrtf(var + 1e-5f);
#pragma unroll
        for (int n = 0; n < 8; n++) {
            float y = fmaf((acc[n][r] - mean) * rstd, gs[n], bs[n]);
            acc[n][r] = relu ? fmaxf(y, 0.f) : y;
        }
    }
}

// ---------------- prep ----------------
__global__ __launch_bounds__(256) void k_prep(
    const float* __restrict__ dW2s, const float* __restrict__ qWs, const float* __restrict__ cW1s,
    const float* __restrict__ cW2s, const float* __restrict__ aWs, const float* __restrict__ lWs,
    const float* __restrict__ actors, const float* __restrict__ metaW,
    const float* __restrict__ dW1s, const float* __restrict__ db1s,
    const float* __restrict__ dg2s, const float* __restrict__ dbt2s,
    const float* __restrict__ qgs, const float* __restrict__ qbs,
    const float* __restrict__ cg1s, const float* __restrict__ cb1s,
    u16* __restrict__ o_dW2p, u16* __restrict__ o_qW, u16* __restrict__ o_cW1p,
    u16* __restrict__ o_cW2, u16* __restrict__ o_aW, u16* __restrict__ o_lW,
    u16* __restrict__ o_actb, u16* __restrict__ o_mWf, float* __restrict__ o_mWe,
    float* __restrict__ o_dw1p, float* __restrict__ o_gb) {
    int idx = blockIdx.x * 256 + threadIdx.x;
    if (idx >= 412672) return;
    if (idx < 32768) {
        int i = idx >> 14, rem = idx & 16383, ro = rem >> 7, col = rem & 127;
        o_dW2p[idx] = f2bf(dW2s[i * 16384 + rowmap(ro >> 4, ro & 15) * 128 + col]);
    } else if (idx < 65536) {
        int j = idx - 32768; o_qW[j] = f2bf(qWs[j]);   // natural (used by nodeA)
    } else if (idx < 163840) {
        int j = idx - 65536, i = j / 49152, rem = j - i * 49152, ro = rem / 384, col = rem - ro * 384;
        o_cW1p[j] = f2bf(cW1s[i * 49152 + rowmap(ro >> 4, ro & 15) * 384 + col]);
    } else if (idx < 196608) { int j = idx - 163840; o_cW2[j] = f2bf(cW2s[j]); }
    else if (idx < 229376) { int j = idx - 196608; o_aW[j] = f2bf(aWs[j]); }
    else if (idx < 262144) { int j = idx - 229376; o_lW[j] = f2bf(lWs[j]); }
    else if (idx < 393216) { int j = idx - 262144; o_actb[j] = f2bf(actors[j]); }
    else if (idx < 409600) { int j = idx - 393216; o_mWf[j] = f2bf(metaW[(j >> 7) * 132 + (j & 127)]); }
    else if (idx < 410112) { int j = idx - 409600; o_mWe[j] = metaW[(j >> 2) * 132 + 128 + (j & 3)]; }
    else if (idx < 411136) {
        int j = idx - 410112, i = j >> 9, col = (j >> 2) & 127, t = j & 3;
        float v = (t == 0) ? dW1s[i * 256 + col * 2]
                : (t == 1) ? dW1s[i * 256 + col * 2 + 1]
                : (t == 2) ? db1s[i * 128 + col] : 0.f;
        o_dw1p[j] = v;
    } else {
        int j = idx - 411136;           // 3 tables x 2 layers x 128 x {g,b}
        int tb = j >> 9, rem = j & 511, i = rem >> 8, q = rem & 255, o = q >> 1, f = q & 1;
        const float* gsrc = (tb == 0) ? dg2s : (tb == 1) ? qgs : cg1s;
        const float* bsrc = (tb == 0) ? dbt2s : (tb == 1) ? qbs : cb1s;
        int src = i * 128 + rowmap(o >> 4, o & 15);
        o_gb[j] = f ? bsrc[src] : gsrc[src];
    }
}

// ---------------- meta (verbatim round 6) ----------------
__global__ __launch_bounds__(256) void k_meta(
    const float* __restrict__ feat, const float* __restrict__ turn,
    const float* __restrict__ ctrl, const float* __restrict__ inter,
    const u16* __restrict__ mWf, const float* __restrict__ mWe,
    const float* __restrict__ g, const float* __restrict__ b, u16* __restrict__ out) {
    int lane = threadIdx.x & 63, wv = threadIdx.x >> 6;
    int c16 = lane & 15, q4 = lane >> 4;
    int m0 = (blockIdx.x * 4 + wv) * 16;
    bf16x8 a[4];
    const float* xr = feat + (size_t)(m0 + c16) * 128 + q4 * 8;
#pragma unroll
    for (int k = 0; k < 4; k++) {
        float4 u0 = *reinterpret_cast<const float4*>(xr + k * 32);
        float4 u1 = *reinterpret_cast<const float4*>(xr + k * 32 + 4);
        union { u16 s[8]; bf16x8 b; } t;
        t.s[0] = f2bf(u0.x); t.s[1] = f2bf(u0.y); t.s[2] = f2bf(u0.z); t.s[3] = f2bf(u0.w);
        t.s[4] = f2bf(u1.x); t.s[5] = f2bf(u1.y); t.s[6] = f2bf(u1.z); t.s[7] = f2bf(u1.w);
        a[k] = t.b;
    }
    f32x4 acc[8] = {};
    gemm_acc<4>(a, mWf, 128, acc, c16, q4);
#pragma unroll
    for (int r = 0; r < 4; r++) {
        int row = m0 + q4 * 4 + r;
        float t0 = turn[2 * row], t1 = turn[2 * row + 1];
        float cv = ctrl[row], iv = inter[row];
#pragma unroll
        for (int n = 0; n < 8; n++) {
            int col = n * 16 + c16;
            float4 we = reinterpret_cast<const float4*>(mWe)[col];
            acc[n][r] += t0 * we.x + t1 * we.y + cv * we.z + iv * we.w;
        }
    }
    gn_c(acc, g, b, true, c16);
#pragma unroll
    for (int r = 0; r < 4; r++) {
        size_t row = m0 + q4 * 4 + r;
#pragma unroll
        for (int n = 0; n < 8; n++) out[row * 128 + n * 16 + c16] = f2bf(acc[n][r]);
    }
}

// ---------------- nodeA (verbatim round 6) ----------------
__global__ __launch_bounds__(256) void k_nodeA(
    const u16* __restrict__ featb, const u16* __restrict__ qW, const u16* __restrict__ aW,
    const float* __restrict__ qg, const float* __restrict__ qb,
    u16* __restrict__ q_out, float* __restrict__ a_out) {
    int lane = threadIdx.x & 63, wv = threadIdx.x >> 6;
    int c16 = lane & 15, q4 = lane >> 4;
    int m0 = (blockIdx.x * 4 + wv) * 16;
    bf16x8 a[4];
    const u16* xr = featb + (size_t)(m0 + c16) * 128 + q4 * 8;
#pragma unroll
    for (int k = 0; k < 4; k++) a[k] = ldg_frag(xr + k * 32);
    f32x4 accq[8] = {}, acca[8] = {};
    gemm_acc<4>(a, qW, 128, accq, c16, q4);
    gemm_acc<4>(a, aW, 128, acca, c16, q4);
#pragma unroll
    for (int r = 0; r < 4; r++) {
        size_t row = m0 + q4 * 4 + r;
#pragma unroll
        for (int n = 0; n < 8; n++) a_out[row * 128 + n * 16 + c16] = acca[n][r];
    }
    gn_c(accq, qg, qb, true, c16);
#pragma unroll
    for (int r = 0; r < 4; r++) {
        size_t row = m0 + q4 * 4 + r;
#pragma unroll
        for (int n = 0; n < 8; n++) q_out[row * 128 + n * 16 + c16] = f2bf(accq[n][r]);
    }
}

// ---------------- edge: static 64KB LDS, two 32KB slots, phased staging ----------------
__global__ __launch_bounds__(256) void k_edge(
    const int* __restrict__ hi, const int* __restrict__ wi,
    const float* __restrict__ mctr, const float* __restrict__ actr,
    const float* __restrict__ dw1p, const u16* __restrict__ dW2p,
    const float* __restrict__ gb_d2,
    const u16* __restrict__ q_node, const u16* __restrict__ actb,
    const u16* __restrict__ cW1p, const float* __restrict__ gb_c1,
    const u16* __restrict__ cW2, float* __restrict__ a_out) {
    __shared__ u16 s0[16384];   // 32 KB slot
    __shared__ u16 s1[16384];   // 32 KB slot
    int tid = threadIdx.x;
    int lane = tid & 63, wv = tid >> 6;
    int c16 = lane & 15, q4 = lane >> 4;
    int bid = (int)blockIdx.x;
    bid = (bid & 7) * 256 + (bid >> 3);  // XCD swizzle (2048 = 8*256, bijective)
    int ebase = bid * 128 + wv * 32;
    int h0 = hi[ebase + c16], w0 = wi[ebase + c16];
    int h1 = hi[ebase + 16 + c16], w1 = wi[ebase + 16 + c16];
    // phase A: dW2 -> s0, cW1 third 0 (d2 cols) -> s1
    stage128<128>(dW2p, s0, tid, 256);
    stage128<384>(cW1p, s1, tid, 256);
    // gathers (global, independent of LDS)
    bf16x8 qf0[4], qf1[4], af0[4], af1[4];
    {
        const u16* qr0 = q_node + (size_t)h0 * 128 + q4 * 8;
        const u16* qr1 = q_node + (size_t)h1 * 128 + q4 * 8;
        const u16* ar0 = actb + (size_t)w0 * 128 + q4 * 8;
        const u16* ar1 = actb + (size_t)w1 * 128 + q4 * 8;
#pragma unroll
        for (int k = 0; k < 4; k++) {
            qf0[k] = ldg_frag(qr0 + k * 32); qf1[k] = ldg_frag(qr1 + k * 32);
            af0[k] = ldg_frag(ar0 + k * 32); af1[k] = ldg_frag(ar1 + k * 32);
        }
    }
    // d1 = relu(d0 @ dW1^T + db1) in B-frag layout
    float dx0 = mctr[2 * h0] - actr[2 * w0], dy0 = mctr[2 * h0 + 1] - actr[2 * w0 + 1];
    float dx1 = mctr[2 * h1] - actr[2 * w1], dy1 = mctr[2 * h1 + 1] - actr[2 * w1 + 1];
    bf16x8 bd0[4], bd1[4];
    const float4* w4p = reinterpret_cast<const float4*>(dw1p);
#pragma unroll
    for (int k = 0; k < 4; k++) {
        union { u16 s[8]; uint4 u; } t0, t1;
#pragma unroll
        for (int j = 0; j < 8; j++) {
            float4 w4 = w4p[k * 32 + q4 * 8 + j];
            t0.s[j] = f2bf(fmaxf(fmaf(dx0, w4.x, fmaf(dy0, w4.y, w4.z)), 0.f));
            t1.s[j] = f2bf(fmaxf(fmaf(dx1, w4.x, fmaf(dy1, w4.y, w4.z)), 0.f));
        }
        bd0[k] = as_frag(t0.u); bd1[k] = as_frag(t1.u);
    }
    __syncthreads();
    // GEMM1: d2 = relu(GN(d1 @ dW2^T)) — swapped, weights from s0
    f32x4 accA[8] = {}, accB[8] = {};
#pragma unroll
    for (int k = 0; k < 4; k++)
#pragma unroll
        for (int t = 0; t < 8; t++) {
            bf16x8 a = lds_w(s0, t * 16 + c16, k * 64 + q4 * 16);
            accA[t] = MFMA(a, bd0[k], accA[t]);
            accB[t] = MFMA(a, bd1[k], accB[t]);
        }
    gn_t(accA, gb_d2, true, q4);
    gn_t(accB, gb_d2, true, q4);
    bf16x8 d2f0[4], d2f1[4];
#pragma unroll
    for (int k = 0; k < 4; k++) {
        d2f0[k] = pack_frag(accA[2 * k], accA[2 * k + 1]);
        d2f1[k] = pack_frag(accB[2 * k], accB[2 * k + 1]);
    }
    // GEMM2 p0: c1 += d2 part (cW1 cols 0..127) from s1
    f32x4 cA[8] = {}, cB[8] = {};
#pragma unroll
    for (int k = 0; k < 4; k++)
#pragma unroll
        for (int t = 0; t < 8; t++) {
            bf16x8 a = lds_w(s1, t * 16 + c16, k * 64 + q4 * 16);
            cA[t] = MFMA(a, d2f0[k], cA[t]);
            cB[t] = MFMA(a, d2f1[k], cB[t]);
        }
    __syncthreads();
    // phase C: cW1 third 1 (q cols) -> s0, third 2 (actor cols) -> s1
    stage128<384>(cW1p + 128, s0, tid, 256);
    stage128<384>(cW1p + 256, s1, tid, 256);
    __syncthreads();
    // GEMM2 p1 (q frags, s0) + p2 (actor frags, s1)
#pragma unroll
    for (int k = 0; k < 4; k++)
#pragma unroll
        for (int t = 0; t < 8; t++) {
            bf16x8 a = lds_w(s0, t * 16 + c16, k * 64 + q4 * 16);
            cA[t] = MFMA(a, qf0[k], cA[t]);
            cB[t] = MFMA(a, qf1[k], cB[t]);
        }
#pragma unroll
    for (int k = 0; k < 4; k++)
#pragma unroll
        for (int t = 0; t < 8; t++) {
            bf16x8 a = lds_w(s1, t * 16 + c16, k * 64 + q4 * 16);
            cA[t] = MFMA(a, af0[k], cA[t]);
            cB[t] = MFMA(a, af1[k], cB[t]);
        }
    __syncthreads();
    // phase E: cW2 -> s0
    stage128<128>(cW2, s0, tid, 256);
    gn_t(cA, gb_c1, true, q4);
    gn_t(cB, gb_c1, true, q4);
    bf16x8 ba0[4], ba1[4];
#pragma unroll
    for (int k = 0; k < 4; k++) {
        ba0[k] = pack_frag(cA[2 * k], cA[2 * k + 1]);
        ba1[k] = pack_frag(cB[2 * k], cB[2 * k + 1]);
    }
    __syncthreads();
    // GEMM3: c2 = c1 @ cW2^T — NORMAL orientation (coalesced scatter), weights from s0
    f32x4 oA[8] = {}, oB[8] = {};
#pragma unroll
    for (int k = 0; k < 4; k++)
#pragma unroll
        for (int n = 0; n < 8; n++) {
            bf16x8 b = lds_w(s0, n * 16 + c16, k * 64 + q4 * 16);
            oA[n] = MFMA(ba0[k], b, oA[n]);
            oB[n] = MFMA(ba1[k], b, oB[n]);
        }
#pragma unroll
    for (int r = 0; r < 4; r++) {
        int hr0 = hi[ebase + q4 * 4 + r];
        int hr1 = hi[ebase + 16 + q4 * 4 + r];
        float* dst0 = a_out + (size_t)hr0 * 128 + c16;
        float* dst1 = a_out + (size_t)hr1 * 128 + c16;
#pragma unroll
        for (int n = 0; n < 8; n++) {
            unsafeAtomicAdd(dst0 + n * 16, oA[n][r]);
            unsafeAtomicAdd(dst1 + n * 16, oB[n][r]);
        }
    }
}

// ---------------- nodeB (verbatim round 6) ----------------
__global__ __launch_bounds__(256) void k_nodeB(
    const float* __restrict__ a_in, const float* __restrict__ gg, const float* __restrict__ gb,
    const u16* __restrict__ lW, const float* __restrict__ lg, const float* __restrict__ lb,
    const u16* __restrict__ res, u16* __restrict__ out_bf, float* __restrict__ out_f32) {
    int lane = threadIdx.x & 63, wv = threadIdx.x >> 6;
    int c16 = lane & 15, q4 = lane >> 4;
    int m0 = (blockIdx.x * 4 + wv) * 16;
    const float* xr = a_in + (size_t)(m0 + c16) * 128 + q4 * 8;
    float x[32];
#pragma unroll
    for (int k = 0; k < 4; k++) {
        float4 u0 = *reinterpret_cast<const float4*>(xr + k * 32);
        float4 u1 = *reinterpret_cast<const float4*>(xr + k * 32 + 4);
        x[k * 8 + 0] = u0.x; x[k * 8 + 1] = u0.y; x[k * 8 + 2] = u0.z; x[k * 8 + 3] = u0.w;
        x[k * 8 + 4] = u1.x; x[k * 8 + 5] = u1.y; x[k * 8 + 6] = u1.z; x[k * 8 + 7] = u1.w;
    }
    float s = 0.f, s2 = 0.f;
#pragma unroll
    for (int t = 0; t < 32; t++) { s += x[t]; s2 = fmaf(x[t], x[t], s2); }
    s += __shfl_xor(s, 16, 64); s += __shfl_xor(s, 32, 64);
    s2 += __shfl_xor(s2, 16, 64); s2 += __shfl_xor(s2, 32, 64);
    float mean = s * (1.f / 128.f);
    float var = fmaf(s2, 1.f / 128.f, -mean * mean);
    float rstd = rsqrtf(var + 1e-5f);
    bf16x8 a[4];
#pragma unroll
    for (int k = 0; k < 4; k++) {
        float4 g0 = *reinterpret_cast<const float4*>(gg + k * 32 + q4 * 8);
        float4 g1 = *reinterpret_cast<const float4*>(gg + k * 32 + q4 * 8 + 4);
        float4 b0 = *reinterpret_cast<const float4*>(gb + k * 32 + q4 * 8);
        float4 b1 = *reinterpret_cast<const float4*>(gb + k * 32 + q4 * 8 + 4);
        float gv[8] = {g0.x, g0.y, g0.z, g0.w, g1.x, g1.y, g1.z, g1.w};
        float bv[8] = {b0.x, b0.y, b0.z, b0.w, b1.x, b1.y, b1.z, b1.w};
        union { u16 s[8]; bf16x8 b; } t;
#pragma unroll
        for (int j = 0; j < 8; j++) {
            float y = fmaf((x[k * 8 + j] - mean) * rstd, gv[j], bv[j]);
            t.s[j] = f2bf(fmaxf(y, 0.f));
        }
        a[k] = t.b;
    }
    f32x4 acc[8] = {};
    gemm_acc<4>(a, lW, 128, acc, c16, q4);
    gn_c(acc, lg, lb, false, c16);
#pragma unroll
    for (int r = 0; r < 4; r++) {
        size_t row = m0 + q4 * 4 + r;
#pragma unroll
        for (int n = 0; n < 8; n++) {
            int col = n * 16 + c16;
            float y = acc[n][r] + bf2f(res[row * 128 + col]);
            y = fmaxf(y, 0.f);
            if (out_bf) out_bf[row * 128 + col] = f2bf(y);
            else out_f32[row * 128 + col] = y;
        }
    }
}

extern "C" void kernel_launch(void* const* d_in, const int* in_sizes, int n_in,
                              void* d_out, int out_size, void* d_ws, size_t ws_size,
                              hipStream_t stream) {
    const float* feat = (const float*)d_in[0];
    const float* turn = (const float*)d_in[1];
    const float* ctrl = (const float*)d_in[2];
    const float* inter = (const float*)d_in[3];
    const float* mctr = (const float*)d_in[4];
    const float* actors = (const float*)d_in[5];
    const float* actr = (const float*)d_in[6];
    const int* hi = (const int*)d_in[7];
    const int* wi = (const int*)d_in[8];
    const float* metaW = (const float*)d_in[9];
    const float* metag = (const float*)d_in[10];
    const float* metab = (const float*)d_in[11];
    const float* dW1 = (const float*)d_in[12];
    const float* db1 = (const float*)d_in[13];
    const float* dW2 = (const float*)d_in[14];
    const float* dg2 = (const float*)d_in[15];
    const float* dbt2 = (const float*)d_in[16];
    const float* qW = (const float*)d_in[17];
    const float* qg = (const float*)d_in[18];
    const float* qb = (const float*)d_in[19];
    const float* cW1 = (const float*)d_in[20];
    const float* cg1 = (const float*)d_in[21];
    const float* cb1 = (const float*)d_in[22];
    const float* cW2 = (const float*)d_in[23];
    const float* aW = (const float*)d_in[24];
    const float* ngg = (const float*)d_in[25];
    const float* ngb = (const float*)d_in[26];
    const float* lW = (const float*)d_in[27];
    const float* lg = (const float*)d_in[28];
    const float* lb = (const float*)d_in[29];

    char* ws = (char*)d_ws;
    u16* feat0 = (u16*)(ws);                    // 33554432 B
    u16* feat1 = (u16*)(ws + 33554432);         // 33554432 B
    u16* qbuf = (u16*)(ws + 67108864);          // 33554432 B
    u16* actb = (u16*)(ws + 100663296);         // 262144 B
    u16* wmWf = (u16*)(ws + 100925440);         // 32768 B
    u16* wdW2p = (u16*)(ws + 100958208);        // 65536 B
    u16* wqW = (u16*)(ws + 101023744);          // 65536 B
    u16* wcW1p = (u16*)(ws + 101089280);        // 196608 B
    u16* wcW2 = (u16*)(ws + 101285888);         // 65536 B
    u16* waW = (u16*)(ws + 101351424);          // 65536 B
    u16* wlW = (u16*)(ws + 101416960);          // 65536 B
    float* wmWe = (float*)(ws + 101482496);     // 2048 B
    float* wdw1p = (float*)(ws + 101484544);    // 4096 B
    float* gball = (float*)(ws + 101488640);    // 6144 B
    float* abuf = (float*)d_out;                // d_out doubles as f32 scatter buffer

    k_prep<<<1613, 256, 0, stream>>>(dW2, qW, cW1, cW2, aW, lW, actors, metaW, dW1, db1,
                                     dg2, dbt2, qg, qb, cg1, cb1,
                                     wdW2p, wqW, wcW1p, wcW2, waW, wlW, actb, wmWf, wmWe,
                                     wdw1p, gball);
    k_meta<<<2048, 256, 0, stream>>>(feat, turn, ctrl, inter, wmWf, wmWe, metag, metab, feat0);
    for (int i = 0; i < 2; i++) {
        const u16* fcur = i ? feat1 : feat0;
        k_nodeA<<<2048, 256, 0, stream>>>(fcur, wqW + i * 16384, waW + i * 16384,
                                          qg + i * 128, qb + i * 128, qbuf, abuf);
        k_edge<<<2048, 256, 0, stream>>>(hi, wi, mctr, actr, wdw1p + i * 512, wdW2p + i * 16384,
                                         gball + i * 256, qbuf, actb,
                                         wcW1p + i * 49152, gball + 1024 + i * 256,
                                         wcW2 + i * 16384, abuf);
        k_nodeB<<<2048, 256, 0, stream>>>(abuf, ngg + i * 128, ngb + i * 128, wlW + i * 16384,
                                          lg + i * 128, lb + i * 128, fcur,
                                          i ? nullptr : feat1, i ? (float*)d_out : nullptr);
    }
}